// Round 24
// baseline (130.777 us; speedup 1.0000x reference)
//
#include <hip/hip_runtime.h>
#include <math.h>

typedef _Float16 half8 __attribute__((ext_vector_type(8)));
typedef _Float16 half4 __attribute__((ext_vector_type(4)));
typedef float f32x4 __attribute__((ext_vector_type(4)));

constexpr int N = 2000;
constexpr int NP = 2048;   // padded row count for f16 tensors
constexpr int H = 8;
constexpr int D = 32;
constexpr float SCL = 25.0f;
constexpr float L2E = 1.4426950408889634f;
constexpr float FM2 = 25.0f * L2E;   // fixed softmax max (log2 domain)

#define MFMA16(a,b,c)  __builtin_amdgcn_mfma_f32_16x16x32_f16((a),(b),(c),0,0,0)
#define MFMA16K(a,b,c) __builtin_amdgcn_mfma_f32_16x16x16f16((a),(b),(c),0,0,0)

__device__ __forceinline__ float fexp2(float x) { return __builtin_amdgcn_exp2f(x); }

// ---- ws layout (byte offsets) ----
// BIAS f32 [2z][8h][2048]        @ 0          (131072 B)   stores -log2(S)-FM2-1
// SIMG f16 [4g][2000][2000]      @ 131072     (32000000 B) 2-head-group attn sums
// F16  Qch,Kch,Qrh,Krh,Vnh [8][2048][32]; Vth [8][32][2048] @ 32131072 (6x1048576 B)
// Wch  f16 [768][256]            @ 38422528   (393216 B)
// Wrh  f16 [768][256]            @ 38815744   (393216 B)
// Mask u8  [2000][2000]          @ 39208960   (4000000 B)   total ~43.2 MB

// ================= K0: convert W to f16 =================
__global__ __launch_bounds__(256) void wconv_kernel(
    const float* __restrict__ Wc, const float* __restrict__ Wr,
    _Float16* __restrict__ Wch, _Float16* __restrict__ Wrh)
{
    const int i = blockIdx.x * 256 + threadIdx.x;  // grid 768 -> 196608 exactly
    Wch[i] = (_Float16)Wc[i];
    Wrh[i] = (_Float16)Wr[i];
}

// ================= K1: QKV projection via MFMA + L2 norm; K pre-scaled by SCL*L2E*score =================
__global__ __launch_bounds__(256) void qkv_kernel(
    const float* __restrict__ xc, const float* __restrict__ xr,
    const _Float16* __restrict__ Wch, const _Float16* __restrict__ Wrh,
    const float* __restrict__ clsScore, const float* __restrict__ fgScore,
    _Float16* __restrict__ Qch, _Float16* __restrict__ Kch,
    _Float16* __restrict__ Qrh, _Float16* __restrict__ Krh,
    _Float16* __restrict__ Vnh, _Float16* __restrict__ Vth,
    float* __restrict__ out)
{
    constexpr int XS = 264;  // xs row stride (halfs), +8 pad
    __shared__ _Float16 xs[16 * XS];
    const int t = threadIdx.x;
    const int n0 = blockIdx.x * 16;
    const int by = blockIdx.y;             // 0..4: (cls q,k,v), (reg q,k)
    const int which = (by < 3) ? by : (by - 3);
    const bool isCls = by < 3;
    const float* x = isCls ? xc : xr;
    const _Float16* Wh = isCls ? Wch : Wrh;

    #pragma unroll
    for (int it = 0; it < 4; ++it) {
        const int f = t + it * 256;        // float4 index over 16x64
        const int row = f >> 6, c4 = f & 63;
        const float4 v = *(const float4*)(x + (size_t)(n0 + row) * 256 + c4 * 4);
        half4 hv; hv[0]=(_Float16)v.x; hv[1]=(_Float16)v.y; hv[2]=(_Float16)v.z; hv[3]=(_Float16)v.w;
        *(half4*)&xs[row * XS + c4 * 4] = hv;
    }
    __syncthreads();

    const int w = t >> 6, l = t & 63;
    const int lr = l & 15, lg = l >> 4;
    const int obase = which * 256 + w * 64;
    f32x4 acc[4] = {{0,0,0,0},{0,0,0,0},{0,0,0,0},{0,0,0,0}};
    for (int k0 = 0; k0 < 256; k0 += 32) {
        const half8 aX = *(const half8*)&xs[lr * XS + k0 + lg * 8];
        #pragma unroll
        for (int s = 0; s < 4; ++s) {
            const half8 bW = *(const half8*)(Wh + (size_t)(obase + s * 16 + lr) * 256 + k0 + lg * 8);
            acc[s] = MFMA16(aX, bW, acc[s]);
        }
    }
    // K row scale factors (rows n0+lg*4+j)
    f32x4 kscale = {1.f,1.f,1.f,1.f};
    if (which == 1) {
        const float* sp = isCls ? clsScore : fgScore;
        kscale = (SCL * L2E) * *(const f32x4*)(sp + n0 + lg*4);
    }
    #pragma unroll
    for (int p = 0; p < 2; ++p) {
        const int h = 2 * w + p;
        float ss[4];
        #pragma unroll
        for (int j = 0; j < 4; ++j) {
            float v = acc[2*p][j]*acc[2*p][j] + acc[2*p+1][j]*acc[2*p+1][j];
            #pragma unroll
            for (int off = 1; off < 16; off <<= 1) v += __shfl_xor(v, off);
            ss[j] = sqrtf(v) + 1e-8f;
        }
        if (which < 2) {
            _Float16* Qd = isCls ? (which == 0 ? Qch : Kch) : (which == 0 ? Qrh : Krh);
            #pragma unroll
            for (int sh = 0; sh < 2; ++sh)
                #pragma unroll
                for (int j = 0; j < 4; ++j)
                    Qd[((size_t)h*NP + n0 + lg*4 + j)*D + sh*16 + lr]
                        = (_Float16)(acc[2*p+sh][j] / ss[j] * kscale[j]);
        } else {
            #pragma unroll
            for (int sh = 0; sh < 2; ++sh) {
                const int d = sh * 16 + lr;
                half4 tv;
                #pragma unroll
                for (int j = 0; j < 4; ++j) {
                    const float raw = acc[2*p+sh][j];
                    Vnh[((size_t)h*NP + n0 + lg*4 + j)*D + d] = (_Float16)(raw / ss[j]);
                    out[(size_t)(n0 + lg*4 + j)*512 + 256 + h*D + d] = raw;
                    tv[j] = (_Float16)raw;
                }
                *(half4*)(Vth + ((size_t)h*D + d)*NP + n0 + lg*4) = tv;
            }
        }
    }
}

// ================= K2: softmax denom -> bias = -log2(S)-FM2-1 (K pre-scaled), hi-occupancy =================
__global__ __launch_bounds__(512) void stats_kernel(
    const _Float16* __restrict__ Qch, const _Float16* __restrict__ Kch,
    const _Float16* __restrict__ Qrh, const _Float16* __restrict__ Krh,
    float* __restrict__ BIAS)
{
    __shared__ float Ssh[2][4][16];
    const int t = threadIdx.x;
    const int w = t >> 6, l = t & 63;
    const int nsub = w >> 2, mq = w & 3;        // 2 n-subtiles x 4 m-quarters
    const int n0 = blockIdx.x * 32 + nsub * 16; // bx in [0,63): rows 2000..2015 harmless
    const int h = blockIdx.y, z = blockIdx.z;
    const _Float16* Q = z ? Qrh : Qch;
    const _Float16* K = z ? Krh : Kch;
    const int lr = l & 15, lg = l >> 4;
    const half8 aQ = *(const half8*)(Q + ((size_t)h*NP + n0 + lr)*D + lg*8);
    float S[4] = {0.f, 0.f, 0.f, 0.f};
    const int mqB0 = (mq == 0) ? 0 : 31*mq;     // 0,31,62,93
    const int mqB1 = (mq == 3) ? 125 : 31*(mq+1);
    half8 bK = *(const half8*)(K + ((size_t)h*NP + mqB0*16 + lr)*D + lg*8);
    for (int ms = mqB0; ms < mqB1; ++ms) {
        const half8 cur = bK;
        if (ms + 1 < mqB1)
            bK = *(const half8*)(K + ((size_t)h*NP + (ms+1)*16 + lr)*D + lg*8);
        f32x4 z4 = {0.f, 0.f, 0.f, 0.f};
        const f32x4 c = MFMA16(aQ, cur, z4);
        #pragma unroll
        for (int j = 0; j < 4; ++j) S[j] += fexp2(c[j] - FM2);
    }
    #pragma unroll
    for (int j = 0; j < 4; ++j) {
        #pragma unroll
        for (int off = 1; off < 16; off <<= 1) S[j] += __shfl_xor(S[j], off);
    }
    if (lr == 0) {
        #pragma unroll
        for (int j = 0; j < 4; ++j) Ssh[nsub][mq][lg*4 + j] = S[j];
    }
    __syncthreads();
    if (t < 32) {
        const int ns = t >> 4, rl = t & 15;
        const int n = blockIdx.x * 32 + ns*16 + rl;
        BIAS[((size_t)z*H + h)*NP + n]
            = -__log2f(Ssh[ns][0][rl] + Ssh[ns][1][rl] + Ssh[ns][2][rl] + Ssh[ns][3][rl]) - FM2 - 1.0f;
    }
}

// ================= K3: mean-over-h of Vn.Vn^T -> u8 mask (MFMA) =================
__global__ __launch_bounds__(256) void vvmask_kernel(
    const _Float16* __restrict__ Vnh, unsigned char* __restrict__ Mask)
{
    const int t = threadIdx.x;
    const int w = t >> 6, l = t & 63;
    const int n0 = blockIdx.y * 16;
    const int m00 = blockIdx.x * 256 + w * 64;
    const int lr = l & 15, lg = l >> 4;
    half8 aV[8];
    #pragma unroll
    for (int h = 0; h < 8; ++h)
        aV[h] = *(const half8*)(Vnh + ((size_t)(h*NP + n0 + lr))*D + lg*8);
    for (int s = 0; s < 4; ++s) {
        const int mb = m00 + s*16;
        f32x4 acc = {0.f, 0.f, 0.f, 0.f};
        #pragma unroll
        for (int h = 0; h < 8; ++h) {
            const half8 bV = *(const half8*)(Vnh + ((size_t)(h*NP + mb + lr))*D + lg*8);
            acc = MFMA16(aV[h], bV, acc);
        }
        const int m = mb + lr;
        if (m < N) {
            #pragma unroll
            for (int j = 0; j < 4; ++j) {
                const int n = n0 + lg*4 + j;
                Mask[(size_t)n*N + m] = (acc[j]*0.125f > 0.75f) ? (unsigned char)1 : (unsigned char)0;
            }
        }
    }
}

// ================= K4: fused attention — 2 heads x 1000 m-cols per block (grid 1000) =================
// Block = (16 q-rows ny, head group g of 2, m-half mh). Chunk-outer/head-inner loop over 4 chunks.
// Coord staged f16 per chunk for both heads (copy-shaped 1KB loads, ny-major page-local grid).
// SIM summed over the 2 heads in registers -> one f16 plane per group (disjoint m-cols per mh).
// PV partial per m-half -> f32 atomicAdd into out (x-region pre-zeroed).
__global__ __launch_bounds__(256) void attn_kernel(
    const _Float16* __restrict__ Kch, const _Float16* __restrict__ Krh,
    const _Float16* __restrict__ Qch, const _Float16* __restrict__ Qrh,
    const _Float16* __restrict__ Vth, const float* __restrict__ coord,
    const float* __restrict__ BIAS,
    _Float16* __restrict__ SIMG, float* __restrict__ out)
{
    constexpr int CW = 264;                       // costage row stride (f16), 256 + 8 pad
    __shared__ _Float16 costage[2][2][16 * CW];   // [buf][head-local][row*CW]  (33.8 KB)

    const int t = threadIdx.x;
    const int w = t >> 6, l = t & 63;
    const int lr = l & 15, lg = l >> 4;
    const int ny = blockIdx.x;             // 0..124  (FAST axis -> sequential rows)
    const int g  = blockIdx.y;             // 0..3 head group
    const int mh = blockIdx.z;             // 0..1 m-half (chunks 4mh..4mh+3)
    const int h0 = g * 2;
    const int n0 = ny * 16;
    const int n  = n0 + lr;                // this lane's q-row (swapped layout)
    const int bs = (n / 10) * 10;
    const int c0 = mh * 4;

    // Q frags + exponent biases for the 2 heads
    half8 aQc[2], aQr[2]; float bC[2], bR[2];
    #pragma unroll
    for (int hl = 0; hl < 2; ++hl) {
        const int h = h0 + hl;
        aQc[hl] = *(const half8*)(Qch + ((size_t)h*NP + n)*D + lg*8);
        aQr[hl] = *(const half8*)(Qrh + ((size_t)h*NP + n)*D + lg*8);
        bC[hl]  = BIAS[(size_t)h*NP + n];
        bR[hl]  = BIAS[(size_t)(H + h)*NP + n];
    }

    // copy-shaped staging: per head, rep i -> one row, 64x16B = 1KB contiguous per wave instr.
    half4 creg[8];
    auto LOADCH = [&](int c) {
        #pragma unroll
        for (int hl = 0; hl < 2; ++hl) {
            #pragma unroll
            for (int i = 0; i < 4; ++i) {
                const int g16 = t + 256*i;
                const int row = g16 >> 6, c4 = g16 & 63;
                const int col = c*256 + c4*4;
                f32x4 v = {0.f,0.f,0.f,0.f};
                if (col < 2000)
                    v = *(const f32x4*)(coord + ((size_t)(h0 + hl)*N + n0 + row)*N + col);
                half4 hv; hv[0]=(_Float16)v[0]; hv[1]=(_Float16)v[1];
                hv[2]=(_Float16)v[2]; hv[3]=(_Float16)v[3];
                creg[hl*4 + i] = hv;
            }
        }
    };
    auto WRITECH = [&](int buf) {
        #pragma unroll
        for (int hl = 0; hl < 2; ++hl) {
            #pragma unroll
            for (int i = 0; i < 4; ++i) {
                const int g16 = t + 256*i;
                const int row = g16 >> 6, c4 = g16 & 63;
                *(half4*)&costage[buf][hl][row*CW + c4*4] = creg[hl*4 + i];
            }
        }
    };

    f32x4 pv0[2] = {{0,0,0,0},{0,0,0,0}};
    f32x4 pv1[2] = {{0,0,0,0},{0,0,0,0}};

    LOADCH(c0);
    WRITECH(0);
    __syncthreads();
    int buf = 0;

    for (int c = c0; c < c0 + 4; ++c) {
        const bool more = (c + 1 < c0 + 4);
        if (more) LOADCH(c + 1);
        __builtin_amdgcn_sched_barrier(0);

        // chunk c has 16 subtiles (13 for c==7); wave w owns 4 (w3 gets 1 on the tail)
        const int nls = (c < 7) ? 4 : ((w < 3) ? 4 : 1);

        float sacc[4][4] = {{0,0,0,0},{0,0,0,0},{0,0,0,0},{0,0,0,0}};  // [subtile][j], 2-head sum

        #pragma unroll
        for (int hl = 0; hl < 2; ++hl) {
            const int h = h0 + hl;
            // group-batched K/V loads (contiguous in m)
            half8 kc[4], kr[4]; half4 v0[4], v1[4];
            #pragma unroll
            for (int i = 0; i < 4; ++i) {
                if (i >= nls) break;
                const int s = c*16 + w*4 + i;
                const int m = s*16;
                const size_t kb = ((size_t)h*NP + m + lr)*D + lg*8;
                kc[i] = *(const half8*)(Kch + kb);
                kr[i] = *(const half8*)(Krh + kb);
                v0[i] = *(const half4*)(Vth + ((size_t)(h*D + lr))*NP + m + lg*4);
                v1[i] = *(const half4*)(Vth + ((size_t)(h*D + 16 + lr))*NP + m + lg*4);
            }
            __builtin_amdgcn_sched_barrier(0);

            #pragma unroll
            for (int i = 0; i < 4; ++i) {
                if (i >= nls) break;
                const int s = c*16 + w*4 + i;
                const half4 coh = *(const half4*)&costage[buf][hl][lr*CW + (w*4 + i)*16 + lg*4];
                f32x4 z4 = {0,0,0,0};
                // swapped operands: lane holds S[q = n][m = s*16 + lg*4 + j]
                const f32x4 cc = MFMA16(kc[i], aQc[hl], z4);
                const f32x4 cr = MFMA16(kr[i], aQr[hl], z4);
                half4 af;
                #pragma unroll
                for (int j = 0; j < 4; ++j) {
                    const int m = s*16 + lg*4 + j;
                    float a = (fexp2(cc[j] + bC[hl]) + fexp2(cr[j] + bR[hl])) * (float)coh[j];
                    if (m >= bs && m < bs + 9 && m != n) a = 0.f;
                    sacc[i][j] += a;
                    af[j] = (_Float16)a;
                }
                pv0[hl] = MFMA16K(af, v0[i], pv0[hl]);
                pv1[hl] = MFMA16K(af, v1[i], pv1[hl]);
            }
        }

        // SIM chunk write: 2-head sums (one f16 plane per group; disjoint m-cols per mh)
        #pragma unroll
        for (int i = 0; i < 4; ++i) {
            if (i >= nls) break;
            const int s = c*16 + w*4 + i;
            half4 sv;
            #pragma unroll
            for (int j = 0; j < 4; ++j) sv[j] = (_Float16)sacc[i][j];
            *(half4*)(SIMG + ((size_t)g*N + n)*N + s*16 + lg*4) = sv;
        }

        if (more) WRITECH(buf ^ 1);
        __syncthreads();
        buf ^= 1;
    }

    // cross-wave PV reduce for 2 heads (alias onto costage; dead after last chunk, barrier-separated)
    float (*pvredH)[4][2][16][17] = (float(*)[4][2][16][17])&costage[0][0][0];
    #pragma unroll
    for (int hl = 0; hl < 2; ++hl)
        #pragma unroll
        for (int j = 0; j < 4; ++j) {
            pvredH[hl][w][0][lr][lg*4 + j] = pv0[hl][j];
            pvredH[hl][w][1][lr][lg*4 + j] = pv1[hl][j];
        }
    __syncthreads();
    for (int e = t; e < 1024; e += 256) {
        const int hl = e >> 9, e2 = e & 511;
        const int d = e2 & 15, db = (e2 >> 4) & 1, q = e2 >> 5;
        const float sum = pvredH[hl][0][db][d][q] + pvredH[hl][1][db][d][q]
                        + pvredH[hl][2][db][d][q] + pvredH[hl][3][db][d][q];
        atomicAdd(&out[(size_t)(n0 + q)*512 + (h0 + hl)*32 + db*16 + d], sum);
    }
}

// ================= K6: row softmax of sum of 4 SIMG planes (/8 folded) + masked renorm =================
__global__ __launch_bounds__(256) void simfinal_kernel(
    const _Float16* __restrict__ SIMG, const unsigned char* __restrict__ Mask,
    float* __restrict__ out)
{
    __shared__ float redA[4], redB[4];
    const int n = blockIdx.x, t = threadIdx.x;
    const unsigned char* mrow = Mask + (size_t)n * N;
    const bool act = t < 250;                 // 250 x 8 halfs = 2000
    float f[8] = {0,0,0,0,0,0,0,0};
    unsigned int mk0 = 0, mk1 = 0;
    float mx = -1e30f;
    if (act) {
        #pragma unroll
        for (int p = 0; p < 4; ++p) {
            const half8 v8 = *(const half8*)(SIMG + (size_t)p*N*N + (size_t)n*N + t*8);
            #pragma unroll
            for (int k = 0; k < 8; ++k) f[k] += (float)v8[k];
        }
        const uint2 mm = *(const uint2*)(mrow + t*8);
        mk0 = mm.x; mk1 = mm.y;
        #pragma unroll
        for (int k = 0; k < 8; ++k) mx = fmaxf(mx, f[k]);
    }
    #pragma unroll
    for (int off = 1; off < 64; off <<= 1) mx = fmaxf(mx, __shfl_xor(mx, off));
    const int wv = t >> 6;
    if ((t & 63) == 0) redA[wv] = mx;
    __syncthreads();
    const float M = fmaxf(fmaxf(redA[0], redA[1]), fmaxf(redA[2], redA[3]));
    float e[8];
    float sA = 0.f, sM = 0.f;
    if (act) {
        #pragma unroll
        for (int k = 0; k < 8; ++k) {
            e[k] = fexp2((f[k] - M) * (L2E * 0.125f));   // /8 mean-scale folded in
            sA += e[k];
            const unsigned int mkb = ((k < 4 ? mk0 : mk1) >> (8*(k & 3))) & 0xffu;
            if (mkb) sM += e[k]; else e[k] = 0.f;
        }
    }
    #pragma unroll
    for (int off = 1; off < 64; off <<= 1) { sA += __shfl_xor(sA, off); sM += __shfl_xor(sM, off); }
    __syncthreads();
    if ((t & 63) == 0) { redA[wv] = sA; redB[wv] = sM; }
    __syncthreads();
    const float SA = redA[0] + redA[1] + redA[2] + redA[3];
    const float SMK = redB[0] + redB[1] + redB[2] + redB[3];
    const float inv = 1.f / (SMK + 1e-8f * SA);
    if (act) {
        float* orow = out + 1024000 + (size_t)n*N + t*8;
        *(float4*)(orow)     = make_float4(e[0]*inv, e[1]*inv, e[2]*inv, e[3]*inv);
        *(float4*)(orow + 4) = make_float4(e[4]*inv, e[5]*inv, e[6]*inv, e[7]*inv);
    }
}

extern "C" void kernel_launch(void* const* d_in, const int* in_sizes, int n_in,
                              void* d_out, int out_size, void* d_ws, size_t ws_size,
                              hipStream_t stream) {
    const float* x_cls     = (const float*)d_in[0];
    const float* x_reg     = (const float*)d_in[1];
    const float* cls_score = (const float*)d_in[2];
    const float* fg_score  = (const float*)d_in[3];
    const float* coord     = (const float*)d_in[4];
    const float* Wc        = (const float*)d_in[5];
    const float* Wr        = (const float*)d_in[6];

    char* base = (char*)d_ws;
    float* BIAS      = (float*)base;
    _Float16* SIMG   = (_Float16*)(base + 131072);
    _Float16* Qch    = (_Float16*)(base + 32131072);
    _Float16* Kch    = Qch + 524288;
    _Float16* Qrh    = Qch + 2*524288;
    _Float16* Krh    = Qch + 3*524288;
    _Float16* Vnh    = Qch + 4*524288;
    _Float16* Vth    = Qch + 5*524288;
    _Float16* Wch    = (_Float16*)(base + 38422528);
    _Float16* Wrh    = (_Float16*)(base + 38815744);
    unsigned char* Mask = (unsigned char*)(base + 39208960);
    float* out = (float*)d_out;

    hipMemsetAsync(out, 0, 1024000 * sizeof(float), stream);  // zero x-region for atomic PV accum
    wconv_kernel<<<768, 256, 0, stream>>>(Wc, Wr, Wch, Wrh);
    qkv_kernel<<<dim3(125, 5), 256, 0, stream>>>(x_cls, x_reg, Wch, Wrh, cls_score, fg_score,
                                                 Qch, Kch, Qrh, Krh, Vnh, Vth, out);
    stats_kernel<<<dim3(63, 8, 2), 512, 0, stream>>>(Qch, Kch, Qrh, Krh, BIAS);
    vvmask_kernel<<<dim3(8, 125), 256, 0, stream>>>(Vnh, Mask);
    attn_kernel<<<dim3(125, 4, 2), 256, 0, stream>>>(Kch, Krh, Qch, Qrh, Vth, coord,
                                                     BIAS, SIMG, out);
    simfinal_kernel<<<2000, 256, 0, stream>>>(SIMG, Mask, out);
}

// Round 25
// 126.740 us; speedup vs baseline: 1.0319x; 1.0319x over previous
//
#include <hip/hip_runtime.h>
#include <math.h>

typedef _Float16 half8 __attribute__((ext_vector_type(8)));
typedef _Float16 half4 __attribute__((ext_vector_type(4)));
typedef float f32x4 __attribute__((ext_vector_type(4)));

constexpr int N = 2000;
constexpr int NP = 2048;   // padded row count for f16 tensors
constexpr int H = 8;
constexpr int D = 32;
constexpr float SCL = 25.0f;
constexpr float L2E = 1.4426950408889634f;
constexpr float FM2 = 25.0f * L2E;   // fixed softmax max (log2 domain)

#define MFMA16(a,b,c)  __builtin_amdgcn_mfma_f32_16x16x32_f16((a),(b),(c),0,0,0)
#define MFMA16K(a,b,c) __builtin_amdgcn_mfma_f32_16x16x16f16((a),(b),(c),0,0,0)

__device__ __forceinline__ float fexp2(float x) { return __builtin_amdgcn_exp2f(x); }

// ---- ws layout (byte offsets) ----
// BIAS f32 [2z][8h][2048]        @ 0          (131072 B)   stores -log2(S)-FM2-1
// SIMG f16 [4g][2000][2000]      @ 131072     (32000000 B) 2-head-group attn sums
// F16  Qch,Kch,Qrh,Krh,Vnh [8][2048][32]; Vth [8][32][2048] @ 32131072 (6x1048576 B)
// Wch  f16 [768][256]            @ 38422528   (393216 B)
// Wrh  f16 [768][256]            @ 38815744   (393216 B)
// Mask u8  [2000][2000]          @ 39208960   (4000000 B)   total ~43.2 MB

// ================= K0: convert W to f16 =================
__global__ __launch_bounds__(256) void wconv_kernel(
    const float* __restrict__ Wc, const float* __restrict__ Wr,
    _Float16* __restrict__ Wch, _Float16* __restrict__ Wrh)
{
    const int i = blockIdx.x * 256 + threadIdx.x;  // grid 768 -> 196608 exactly
    Wch[i] = (_Float16)Wc[i];
    Wrh[i] = (_Float16)Wr[i];
}

// ================= K1: QKV projection via MFMA + L2 norm; K pre-scaled by SCL*L2E*score =================
__global__ __launch_bounds__(256) void qkv_kernel(
    const float* __restrict__ xc, const float* __restrict__ xr,
    const _Float16* __restrict__ Wch, const _Float16* __restrict__ Wrh,
    const float* __restrict__ clsScore, const float* __restrict__ fgScore,
    _Float16* __restrict__ Qch, _Float16* __restrict__ Kch,
    _Float16* __restrict__ Qrh, _Float16* __restrict__ Krh,
    _Float16* __restrict__ Vnh, _Float16* __restrict__ Vth,
    float* __restrict__ out)
{
    constexpr int XS = 264;  // xs row stride (halfs), +8 pad
    __shared__ _Float16 xs[16 * XS];
    const int t = threadIdx.x;
    const int n0 = blockIdx.x * 16;
    const int by = blockIdx.y;             // 0..4: (cls q,k,v), (reg q,k)
    const int which = (by < 3) ? by : (by - 3);
    const bool isCls = by < 3;
    const float* x = isCls ? xc : xr;
    const _Float16* Wh = isCls ? Wch : Wrh;

    #pragma unroll
    for (int it = 0; it < 4; ++it) {
        const int f = t + it * 256;        // float4 index over 16x64
        const int row = f >> 6, c4 = f & 63;
        const float4 v = *(const float4*)(x + (size_t)(n0 + row) * 256 + c4 * 4);
        half4 hv; hv[0]=(_Float16)v.x; hv[1]=(_Float16)v.y; hv[2]=(_Float16)v.z; hv[3]=(_Float16)v.w;
        *(half4*)&xs[row * XS + c4 * 4] = hv;
    }
    __syncthreads();

    const int w = t >> 6, l = t & 63;
    const int lr = l & 15, lg = l >> 4;
    const int obase = which * 256 + w * 64;
    f32x4 acc[4] = {{0,0,0,0},{0,0,0,0},{0,0,0,0},{0,0,0,0}};
    for (int k0 = 0; k0 < 256; k0 += 32) {
        const half8 aX = *(const half8*)&xs[lr * XS + k0 + lg * 8];
        #pragma unroll
        for (int s = 0; s < 4; ++s) {
            const half8 bW = *(const half8*)(Wh + (size_t)(obase + s * 16 + lr) * 256 + k0 + lg * 8);
            acc[s] = MFMA16(aX, bW, acc[s]);
        }
    }
    // K row scale factors (rows n0+lg*4+j)
    f32x4 kscale = {1.f,1.f,1.f,1.f};
    if (which == 1) {
        const float* sp = isCls ? clsScore : fgScore;
        kscale = (SCL * L2E) * *(const f32x4*)(sp + n0 + lg*4);
    }
    #pragma unroll
    for (int p = 0; p < 2; ++p) {
        const int h = 2 * w + p;
        float ss[4];
        #pragma unroll
        for (int j = 0; j < 4; ++j) {
            float v = acc[2*p][j]*acc[2*p][j] + acc[2*p+1][j]*acc[2*p+1][j];
            #pragma unroll
            for (int off = 1; off < 16; off <<= 1) v += __shfl_xor(v, off);
            ss[j] = sqrtf(v) + 1e-8f;
        }
        if (which < 2) {
            _Float16* Qd = isCls ? (which == 0 ? Qch : Kch) : (which == 0 ? Qrh : Krh);
            #pragma unroll
            for (int sh = 0; sh < 2; ++sh)
                #pragma unroll
                for (int j = 0; j < 4; ++j)
                    Qd[((size_t)h*NP + n0 + lg*4 + j)*D + sh*16 + lr]
                        = (_Float16)(acc[2*p+sh][j] / ss[j] * kscale[j]);
        } else {
            #pragma unroll
            for (int sh = 0; sh < 2; ++sh) {
                const int d = sh * 16 + lr;
                half4 tv;
                #pragma unroll
                for (int j = 0; j < 4; ++j) {
                    const float raw = acc[2*p+sh][j];
                    Vnh[((size_t)h*NP + n0 + lg*4 + j)*D + d] = (_Float16)(raw / ss[j]);
                    out[(size_t)(n0 + lg*4 + j)*512 + 256 + h*D + d] = raw;
                    tv[j] = (_Float16)raw;
                }
                *(half4*)(Vth + ((size_t)h*D + d)*NP + n0 + lg*4) = tv;
            }
        }
    }
}

// ================= K2: softmax denom -> bias = -log2(S)-FM2-1 (K pre-scaled), hi-occupancy =================
__global__ __launch_bounds__(512) void stats_kernel(
    const _Float16* __restrict__ Qch, const _Float16* __restrict__ Kch,
    const _Float16* __restrict__ Qrh, const _Float16* __restrict__ Krh,
    float* __restrict__ BIAS)
{
    __shared__ float Ssh[2][4][16];
    const int t = threadIdx.x;
    const int w = t >> 6, l = t & 63;
    const int nsub = w >> 2, mq = w & 3;        // 2 n-subtiles x 4 m-quarters
    const int n0 = blockIdx.x * 32 + nsub * 16; // bx in [0,63): rows 2000..2015 harmless
    const int h = blockIdx.y, z = blockIdx.z;
    const _Float16* Q = z ? Qrh : Qch;
    const _Float16* K = z ? Krh : Kch;
    const int lr = l & 15, lg = l >> 4;
    const half8 aQ = *(const half8*)(Q + ((size_t)h*NP + n0 + lr)*D + lg*8);
    float S[4] = {0.f, 0.f, 0.f, 0.f};
    const int mqB0 = (mq == 0) ? 0 : 31*mq;     // 0,31,62,93
    const int mqB1 = (mq == 3) ? 125 : 31*(mq+1);
    half8 bK = *(const half8*)(K + ((size_t)h*NP + mqB0*16 + lr)*D + lg*8);
    for (int ms = mqB0; ms < mqB1; ++ms) {
        const half8 cur = bK;
        if (ms + 1 < mqB1)
            bK = *(const half8*)(K + ((size_t)h*NP + (ms+1)*16 + lr)*D + lg*8);
        f32x4 z4 = {0.f, 0.f, 0.f, 0.f};
        const f32x4 c = MFMA16(aQ, cur, z4);
        #pragma unroll
        for (int j = 0; j < 4; ++j) S[j] += fexp2(c[j] - FM2);
    }
    #pragma unroll
    for (int j = 0; j < 4; ++j) {
        #pragma unroll
        for (int off = 1; off < 16; off <<= 1) S[j] += __shfl_xor(S[j], off);
    }
    if (lr == 0) {
        #pragma unroll
        for (int j = 0; j < 4; ++j) Ssh[nsub][mq][lg*4 + j] = S[j];
    }
    __syncthreads();
    if (t < 32) {
        const int ns = t >> 4, rl = t & 15;
        const int n = blockIdx.x * 32 + ns*16 + rl;
        BIAS[((size_t)z*H + h)*NP + n]
            = -__log2f(Ssh[ns][0][rl] + Ssh[ns][1][rl] + Ssh[ns][2][rl] + Ssh[ns][3][rl]) - FM2 - 1.0f;
    }
}

// ================= K3: mean-over-h of Vn.Vn^T -> u8 mask (MFMA) =================
__global__ __launch_bounds__(256) void vvmask_kernel(
    const _Float16* __restrict__ Vnh, unsigned char* __restrict__ Mask)
{
    const int t = threadIdx.x;
    const int w = t >> 6, l = t & 63;
    const int n0 = blockIdx.y * 16;
    const int m00 = blockIdx.x * 256 + w * 64;
    const int lr = l & 15, lg = l >> 4;
    half8 aV[8];
    #pragma unroll
    for (int h = 0; h < 8; ++h)
        aV[h] = *(const half8*)(Vnh + ((size_t)(h*NP + n0 + lr))*D + lg*8);
    for (int s = 0; s < 4; ++s) {
        const int mb = m00 + s*16;
        f32x4 acc = {0.f, 0.f, 0.f, 0.f};
        #pragma unroll
        for (int h = 0; h < 8; ++h) {
            const half8 bV = *(const half8*)(Vnh + ((size_t)(h*NP + mb + lr))*D + lg*8);
            acc = MFMA16(aV[h], bV, acc);
        }
        const int m = mb + lr;
        if (m < N) {
            #pragma unroll
            for (int j = 0; j < 4; ++j) {
                const int n = n0 + lg*4 + j;
                Mask[(size_t)n*N + m] = (acc[j]*0.125f > 0.75f) ? (unsigned char)1 : (unsigned char)0;
            }
        }
    }
}

// ================= K4: fused attention — 2 heads/block (grid 500), register head-summed SIM =================
// Block = (16 q-rows ny, head group g of 2) x all 2000 m. Chunk-outer/head-inner loop.
// Coord staged f16 per chunk for both heads (copy-shaped 1KB loads, ny-major page-local grid).
// SIM summed over the 2 heads in registers -> one f16 plane per group (halves SIM vs per-head).
__global__ __launch_bounds__(256) void attn_kernel(
    const _Float16* __restrict__ Kch, const _Float16* __restrict__ Krh,
    const _Float16* __restrict__ Qch, const _Float16* __restrict__ Qrh,
    const _Float16* __restrict__ Vth, const float* __restrict__ coord,
    const float* __restrict__ BIAS,
    _Float16* __restrict__ SIMG, float* __restrict__ out)
{
    constexpr int CW = 264;                       // costage row stride (f16), 256 + 8 pad
    __shared__ _Float16 costage[2][2][16 * CW];   // [buf][head-local][row*CW]  (33.8 KB)

    const int t = threadIdx.x;
    const int w = t >> 6, l = t & 63;
    const int lr = l & 15, lg = l >> 4;
    const int ny = blockIdx.x;             // 0..124  (FAST axis -> sequential rows)
    const int g  = blockIdx.y;             // 0..3 head group
    const int h0 = g * 2;
    const int n0 = ny * 16;
    const int n  = n0 + lr;                // this lane's q-row (swapped layout)
    const int bs = (n / 10) * 10;

    // Q frags + exponent biases for the 2 heads
    half8 aQc[2], aQr[2]; float bC[2], bR[2];
    #pragma unroll
    for (int hl = 0; hl < 2; ++hl) {
        const int h = h0 + hl;
        aQc[hl] = *(const half8*)(Qch + ((size_t)h*NP + n)*D + lg*8);
        aQr[hl] = *(const half8*)(Qrh + ((size_t)h*NP + n)*D + lg*8);
        bC[hl]  = BIAS[(size_t)h*NP + n];
        bR[hl]  = BIAS[(size_t)(H + h)*NP + n];
    }

    // copy-shaped staging: per head, rep i -> one row, 64x16B = 1KB contiguous per wave instr.
    half4 creg[8];
    auto LOADCH = [&](int c) {
        #pragma unroll
        for (int hl = 0; hl < 2; ++hl) {
            #pragma unroll
            for (int i = 0; i < 4; ++i) {
                const int g16 = t + 256*i;
                const int row = g16 >> 6, c4 = g16 & 63;
                const int col = c*256 + c4*4;
                f32x4 v = {0.f,0.f,0.f,0.f};
                if (col < 2000)
                    v = *(const f32x4*)(coord + ((size_t)(h0 + hl)*N + n0 + row)*N + col);
                half4 hv; hv[0]=(_Float16)v[0]; hv[1]=(_Float16)v[1];
                hv[2]=(_Float16)v[2]; hv[3]=(_Float16)v[3];
                creg[hl*4 + i] = hv;
            }
        }
    };
    auto WRITECH = [&](int buf) {
        #pragma unroll
        for (int hl = 0; hl < 2; ++hl) {
            #pragma unroll
            for (int i = 0; i < 4; ++i) {
                const int g16 = t + 256*i;
                const int row = g16 >> 6, c4 = g16 & 63;
                *(half4*)&costage[buf][hl][row*CW + c4*4] = creg[hl*4 + i];
            }
        }
    };

    f32x4 pv0[2] = {{0,0,0,0},{0,0,0,0}};
    f32x4 pv1[2] = {{0,0,0,0},{0,0,0,0}};

    LOADCH(0);
    WRITECH(0);
    __syncthreads();
    int buf = 0;

    for (int c = 0; c < 8; ++c) {
        const bool more = (c + 1 < 8);
        if (more) LOADCH(c + 1);
        __builtin_amdgcn_sched_barrier(0);

        // chunk c has 16 subtiles (13 for c==7); wave w owns 4 (w3 gets 1 on the tail)
        const int nls = (c < 7) ? 4 : ((w < 3) ? 4 : 1);

        float sacc[4][4] = {{0,0,0,0},{0,0,0,0},{0,0,0,0},{0,0,0,0}};  // [subtile][j], 2-head sum

        #pragma unroll
        for (int hl = 0; hl < 2; ++hl) {
            const int h = h0 + hl;
            // group-batched K/V loads (contiguous in m)
            half8 kc[4], kr[4]; half4 v0[4], v1[4];
            #pragma unroll
            for (int i = 0; i < 4; ++i) {
                if (i >= nls) break;
                const int s = c*16 + w*4 + i;
                const int m = s*16;
                const size_t kb = ((size_t)h*NP + m + lr)*D + lg*8;
                kc[i] = *(const half8*)(Kch + kb);
                kr[i] = *(const half8*)(Krh + kb);
                v0[i] = *(const half4*)(Vth + ((size_t)(h*D + lr))*NP + m + lg*4);
                v1[i] = *(const half4*)(Vth + ((size_t)(h*D + 16 + lr))*NP + m + lg*4);
            }
            __builtin_amdgcn_sched_barrier(0);

            #pragma unroll
            for (int i = 0; i < 4; ++i) {
                if (i >= nls) break;
                const int s = c*16 + w*4 + i;
                const half4 coh = *(const half4*)&costage[buf][hl][lr*CW + (w*4 + i)*16 + lg*4];
                f32x4 z4 = {0,0,0,0};
                // swapped operands: lane holds S[q = n][m = s*16 + lg*4 + j]
                const f32x4 cc = MFMA16(kc[i], aQc[hl], z4);
                const f32x4 cr = MFMA16(kr[i], aQr[hl], z4);
                half4 af;
                #pragma unroll
                for (int j = 0; j < 4; ++j) {
                    const int m = s*16 + lg*4 + j;
                    float a = (fexp2(cc[j] + bC[hl]) + fexp2(cr[j] + bR[hl])) * (float)coh[j];
                    if (m >= bs && m < bs + 9 && m != n) a = 0.f;
                    sacc[i][j] += a;
                    af[j] = (_Float16)a;
                }
                pv0[hl] = MFMA16K(af, v0[i], pv0[hl]);
                pv1[hl] = MFMA16K(af, v1[i], pv1[hl]);
            }
        }

        // SIM chunk write: 2-head sums (one f16 plane per group)
        #pragma unroll
        for (int i = 0; i < 4; ++i) {
            if (i >= nls) break;
            const int s = c*16 + w*4 + i;
            half4 sv;
            #pragma unroll
            for (int j = 0; j < 4; ++j) sv[j] = (_Float16)sacc[i][j];
            *(half4*)(SIMG + ((size_t)g*N + n)*N + s*16 + lg*4) = sv;
        }

        if (more) WRITECH(buf ^ 1);
        __syncthreads();
        buf ^= 1;
    }

    // cross-wave PV reduce for 2 heads (alias onto costage; dead after last chunk, barrier-separated)
    float (*pvredH)[4][2][16][17] = (float(*)[4][2][16][17])&costage[0][0][0];
    #pragma unroll
    for (int hl = 0; hl < 2; ++hl)
        #pragma unroll
        for (int j = 0; j < 4; ++j) {
            pvredH[hl][w][0][lr][lg*4 + j] = pv0[hl][j];
            pvredH[hl][w][1][lr][lg*4 + j] = pv1[hl][j];
        }
    __syncthreads();
    for (int e = t; e < 1024; e += 256) {
        const int hl = e >> 9, e2 = e & 511;
        const int d = e2 & 15, db = (e2 >> 4) & 1, q = e2 >> 5;
        const float sum = pvredH[hl][0][db][d][q] + pvredH[hl][1][db][d][q]
                        + pvredH[hl][2][db][d][q] + pvredH[hl][3][db][d][q];
        out[(size_t)(n0 + q)*512 + (h0 + hl)*32 + db*16 + d] = sum;
    }
}

// ================= K6: row softmax of sum of 4 SIMG planes (/8 folded) + masked renorm =================
__global__ __launch_bounds__(256) void simfinal_kernel(
    const _Float16* __restrict__ SIMG, const unsigned char* __restrict__ Mask,
    float* __restrict__ out)
{
    __shared__ float redA[4], redB[4];
    const int n = blockIdx.x, t = threadIdx.x;
    const unsigned char* mrow = Mask + (size_t)n * N;
    const bool act = t < 250;                 // 250 x 8 halfs = 2000
    float f[8] = {0,0,0,0,0,0,0,0};
    unsigned int mk0 = 0, mk1 = 0;
    float mx = -1e30f;
    if (act) {
        #pragma unroll
        for (int p = 0; p < 4; ++p) {
            const half8 v8 = *(const half8*)(SIMG + (size_t)p*N*N + (size_t)n*N + t*8);
            #pragma unroll
            for (int k = 0; k < 8; ++k) f[k] += (float)v8[k];
        }
        const uint2 mm = *(const uint2*)(mrow + t*8);
        mk0 = mm.x; mk1 = mm.y;
        #pragma unroll
        for (int k = 0; k < 8; ++k) mx = fmaxf(mx, f[k]);
    }
    #pragma unroll
    for (int off = 1; off < 64; off <<= 1) mx = fmaxf(mx, __shfl_xor(mx, off));
    const int wv = t >> 6;
    if ((t & 63) == 0) redA[wv] = mx;
    __syncthreads();
    const float M = fmaxf(fmaxf(redA[0], redA[1]), fmaxf(redA[2], redA[3]));
    float e[8];
    float sA = 0.f, sM = 0.f;
    if (act) {
        #pragma unroll
        for (int k = 0; k < 8; ++k) {
            e[k] = fexp2((f[k] - M) * (L2E * 0.125f));   // /8 mean-scale folded in
            sA += e[k];
            const unsigned int mkb = ((k < 4 ? mk0 : mk1) >> (8*(k & 3))) & 0xffu;
            if (mkb) sM += e[k]; else e[k] = 0.f;
        }
    }
    #pragma unroll
    for (int off = 1; off < 64; off <<= 1) { sA += __shfl_xor(sA, off); sM += __shfl_xor(sM, off); }
    __syncthreads();
    if ((t & 63) == 0) { redA[wv] = sA; redB[wv] = sM; }
    __syncthreads();
    const float SA = redA[0] + redA[1] + redA[2] + redA[3];
    const float SMK = redB[0] + redB[1] + redB[2] + redB[3];
    const float inv = 1.f / (SMK + 1e-8f * SA);
    if (act) {
        float* orow = out + 1024000 + (size_t)n*N + t*8;
        *(float4*)(orow)     = make_float4(e[0]*inv, e[1]*inv, e[2]*inv, e[3]*inv);
        *(float4*)(orow + 4) = make_float4(e[4]*inv, e[5]*inv, e[6]*inv, e[7]*inv);
    }
}

extern "C" void kernel_launch(void* const* d_in, const int* in_sizes, int n_in,
                              void* d_out, int out_size, void* d_ws, size_t ws_size,
                              hipStream_t stream) {
    const float* x_cls     = (const float*)d_in[0];
    const float* x_reg     = (const float*)d_in[1];
    const float* cls_score = (const float*)d_in[2];
    const float* fg_score  = (const float*)d_in[3];
    const float* coord     = (const float*)d_in[4];
    const float* Wc        = (const float*)d_in[5];
    const float* Wr        = (const float*)d_in[6];

    char* base = (char*)d_ws;
    float* BIAS      = (float*)base;
    _Float16* SIMG   = (_Float16*)(base + 131072);
    _Float16* Qch    = (_Float16*)(base + 32131072);
    _Float16* Kch    = Qch + 524288;
    _Float16* Qrh    = Qch + 2*524288;
    _Float16* Krh    = Qch + 3*524288;
    _Float16* Vnh    = Qch + 4*524288;
    _Float16* Vth    = Qch + 5*524288;
    _Float16* Wch    = (_Float16*)(base + 38422528);
    _Float16* Wrh    = (_Float16*)(base + 38815744);
    unsigned char* Mask = (unsigned char*)(base + 39208960);
    float* out = (float*)d_out;

    wconv_kernel<<<768, 256, 0, stream>>>(Wc, Wr, Wch, Wrh);
    qkv_kernel<<<dim3(125, 5), 256, 0, stream>>>(x_cls, x_reg, Wch, Wrh, cls_score, fg_score,
                                                 Qch, Kch, Qrh, Krh, Vnh, Vth, out);
    stats_kernel<<<dim3(63, 8, 2), 512, 0, stream>>>(Qch, Kch, Qrh, Krh, BIAS);
    vvmask_kernel<<<dim3(8, 125), 256, 0, stream>>>(Vnh, Mask);
    attn_kernel<<<dim3(125, 4), 256, 0, stream>>>(Kch, Krh, Qch, Qrh, Vth, coord,
                                                  BIAS, SIMG, out);
    simfinal_kernel<<<2000, 256, 0, stream>>>(SIMG, Mask, out);
}